// Round 4
// baseline (274.478 us; speedup 1.0000x reference)
//
#include <hip/hip_runtime.h>

// NCC loss: 1 - mean( cross^2 / (pvar*tvar + 1e-8) ) over 9^3 zero-padded
// box windows, input (4,1,160,160,160) fp32.
//
// R4: R3 was serialization-bound on wave 0's y+cc pass (80 ds_read_b32,
// 4-way bank-conflicted: s2 stride 20 -> yq groups 160 floats ≡ 0 mod 32).
// Changes:
//  - s2 TRANSPOSED to [field][x][y], x-stride 28 floats (112 B): y+cc reads
//    become 3 aligned ds_read_b128 per field (15 total vs 80 b32), banks
//    <=2-way (free). x-pass writes become 20 scattered b32 over 3 waves,
//    also <=2-way banked.
//  - global prefetch issued BEFORE the DPP x-pass (more overlap).
//  - everything else (register DPP x-pass, LDS slice ring, 2 barriers) as R3.

#define DSZ    160
#define NBATCH 4
#define RAD    4
#define TX     16
#define TY     16
#define ZCHUNK 40
#define NZC    (DSZ/ZCHUNK)    // 4
#define SLICE  (DSZ*DSZ)
#define VOL    (DSZ*DSZ*DSZ)
#define WINV   (1.0f/729.0f)
#define NVOX_INV (1.0f/16384000.0f)

#define NROW 24        // halo rows per tile
#define NGRP 6         // x groups of 4 halo cols (24)
#define BLK  192
#define NSTG 144       // staging threads

#define S2_XS 28               // s2 per-x stride in floats (24 y + pad to 28)
#define S2_FS (16*S2_XS)       // 448 floats per field

__device__ __forceinline__ float dpp_shl1(float x) {  // lane i <- lane i+1 (16-lane row, OOB=0)
    return __int_as_float(__builtin_amdgcn_update_dpp(0, __float_as_int(x), 0x101, 0xf, 0xf, true));
}
__device__ __forceinline__ float dpp_shl2(float x) {  // lane i <- lane i+2
    return __int_as_float(__builtin_amdgcn_update_dpp(0, __float_as_int(x), 0x102, 0xf, 0xf, true));
}

__global__ __launch_bounds__(BLK)
void ncc_main(const float* __restrict__ pred, const float* __restrict__ tgt,
              float* __restrict__ accum)
{
    const int tid = threadIdx.x;
    const int row = tid >> 3;      // 0..23 halo row
    const int g   = tid & 7;       // 0..7; g<6 = active x-group
    const int ox  = blockIdx.x * TX;
    const int oy  = blockIdx.y * TY;
    const int batch = blockIdx.z >> 2;
    const int z0  = (blockIdx.z & 3) * ZCHUNK;

    __shared__ float s2[5*S2_FS];        // 8.96 KB, [field][x][y(pad 28)]
    __shared__ float ring[9*NSTG*8];     // 41.5 KB, [slot][st][p0..3,t0..3]

    const bool stg = (g < NGRP);
    const int  gy  = oy - RAD + row;
    const int  gx0 = ox - RAD + g*4;
    const bool ldok = stg && (gy >= 0) && (gy < DSZ) && (gx0 >= 0) && (gx0 + 3 < DSZ);
    const int  base = batch*VOL + gy*DSZ + gx0;     // only used under ldok
    const int  st   = row*NGRP + g;                 // staging index (stg only)

    // z-window sums for own 4 columns x 5 fields, in registers
    float zs[5][4];
    #pragma unroll
    for (int f = 0; f < 5; ++f)
        #pragma unroll
        for (int j = 0; j < 4; ++j) zs[f][j] = 0.f;

    // ---- warm-up: slices [z0-4, z0+3] -> fold add + store raw to ring ----
    for (int z = z0 - RAD; z < z0 + RAD; ++z) {
        if (z < 0) continue;
        float4 p4 = {0,0,0,0}, t4 = {0,0,0,0};
        if (ldok) {
            p4 = *(const float4*)(pred + base + z*SLICE);
            t4 = *(const float4*)(tgt  + base + z*SLICE);
        }
        if (stg) {
            const float pc[4] = {p4.x,p4.y,p4.z,p4.w};
            const float tc[4] = {t4.x,t4.y,t4.z,t4.w};
            #pragma unroll
            for (int j = 0; j < 4; ++j) {
                zs[0][j] += pc[j];        zs[1][j] += tc[j];
                zs[2][j] += pc[j]*pc[j];  zs[3][j] += tc[j]*tc[j];
                zs[4][j] += pc[j]*tc[j];
            }
            float4* w4 = (float4*)&ring[((z % 9)*NSTG + st)*8];
            w4[0] = p4; w4[1] = t4;
        }
    }

    // ---- prefetch of the add slice (z = zo+4) ----
    float4 pa4 = {0,0,0,0}, ta4 = {0,0,0,0};
    auto pf = [&](int zo) {
        int za = zo + RAD;
        float4 p = {0,0,0,0}, t = {0,0,0,0};
        if (ldok && za < DSZ) {
            p = *(const float4*)(pred + base + za*SLICE);
            t = *(const float4*)(tgt  + base + za*SLICE);
        }
        pa4 = p; ta4 = t;
    };
    if (stg) pf(z0);

    float acc = 0.f;

    for (int zo = z0; zo < z0 + ZCHUNK; ++zo) {
        if (stg) {
            // subtract slice zo-5 from ring (loaded 9 steps ago)
            int zsub = zo - 5;
            if (zsub >= 0 && zsub >= z0 - RAD) {
                const float4* r4 = (const float4*)&ring[((zsub % 9)*NSTG + st)*8];
                float4 ps = r4[0], ts = r4[1];
                const float pc[4] = {ps.x,ps.y,ps.z,ps.w};
                const float tc[4] = {ts.x,ts.y,ts.z,ts.w};
                #pragma unroll
                for (int j = 0; j < 4; ++j) {
                    zs[0][j] -= pc[j];        zs[1][j] -= tc[j];
                    zs[2][j] -= pc[j]*pc[j];  zs[3][j] -= tc[j]*tc[j];
                    zs[4][j] -= pc[j]*tc[j];
                }
            }
            // add prefetched slice zo+4; store raw to ring (same slot, after read)
            {
                const float pc[4] = {pa4.x,pa4.y,pa4.z,pa4.w};
                const float tc[4] = {ta4.x,ta4.y,ta4.z,ta4.w};
                #pragma unroll
                for (int j = 0; j < 4; ++j) {
                    zs[0][j] += pc[j];        zs[1][j] += tc[j];
                    zs[2][j] += pc[j]*pc[j];  zs[3][j] += tc[j]*tc[j];
                    zs[4][j] += pc[j]*tc[j];
                }
                int za = zo + RAD;
                if (za < DSZ) {
                    float4* w4 = (float4*)&ring[((za % 9)*NSTG + st)*8];
                    w4[0] = pa4; w4[1] = ta4;
                }
            }

            // issue next step's global loads NOW; they drain behind barrier A
            if (zo + 1 < z0 + ZCHUNK) pf(zo + 1);

            // x 9-sum in registers via group prefix + DPP neighbor fetch;
            // write transposed: s2[f][x][y=row]
            #pragma unroll
            for (int f = 0; f < 5; ++f) {
                float P0 = zs[f][0];
                float P1 = P0 + zs[f][1];
                float P2 = P1 + zs[f][2];
                float P3 = P2 + zs[f][3];
                float T  = dpp_shl1(P3);   // full sum of group g+1
                float Q0 = dpp_shl2(P0);   // prefixes of group g+2
                float Q1 = dpp_shl2(P1);
                float Q2 = dpp_shl2(P2);
                float Q3 = dpp_shl2(P3);
                if (g < 4) {               // output groups 0..3 (x = 4g+i)
                    float b = P3 + T;
                    float* dst = &s2[f*S2_FS + (g*4)*S2_XS + row];
                    dst[0*S2_XS] = b + Q0;
                    dst[1*S2_XS] = b - P0 + Q1;
                    dst[2*S2_XS] = b - P1 + Q2;
                    dst[3*S2_XS] = b - P2 + Q3;
                }
            }
        }
        __syncthreads();   // A: s2 ready

        // fused y 9-sum + cc: 64 tasks, each 4 voxels; 3 b128 per field
        if (tid < 64) {
            const int x  = tid & 15;
            const int yq = (tid >> 4) * 4;
            float S[5][4];
            #pragma unroll
            for (int f = 0; f < 5; ++f) {
                const float* colp = &s2[f*S2_FS + x*S2_XS + yq];
                float4 a = *(const float4*)(colp + 0);
                float4 bq = *(const float4*)(colp + 4);
                float4 c = *(const float4*)(colp + 8);
                float run = a.x+a.y+a.z+a.w + bq.x+bq.y+bq.z+bq.w + c.x;
                S[f][0] = run;
                run += c.y - a.x;  S[f][1] = run;
                run += c.z - a.y;  S[f][2] = run;
                run += c.w - a.z;  S[f][3] = run;
            }
            #pragma unroll
            for (int i = 0; i < 4; ++i) {
                float Sp = S[0][i], St = S[1][i];
                float Spp = S[2][i], Stt = S[3][i], Spt = S[4][i];
                float cross = Spt - Sp*St*WINV;
                float pv    = Spp - Sp*Sp*WINV;
                float tv    = Stt - St*St*WINV;
                acc += cross*cross / (pv*tv + 1e-8f);
            }
        }
        __syncthreads();   // B: s2 consumed; next step may rewrite
    }

    // wave 0 holds all cc partials
    if (tid < 64) {
        float v = acc;
        #pragma unroll
        for (int off = 32; off > 0; off >>= 1) v += __shfl_down(v, off, 64);
        if (tid == 0) atomicAdd(accum, v);
    }
}

__global__ void ncc_final(const float* __restrict__ accum, float* __restrict__ out)
{
    out[0] = 1.0f - accum[0] * NVOX_INV;
}

extern "C" void kernel_launch(void* const* d_in, const int* in_sizes, int n_in,
                              void* d_out, int out_size, void* d_ws, size_t ws_size,
                              hipStream_t stream)
{
    const float* pred = (const float*)d_in[0];
    const float* tgt  = (const float*)d_in[1];
    float* out = (float*)d_out;
    float* ws  = (float*)d_ws;

    hipMemsetAsync(ws, 0, sizeof(float), stream);
    dim3 grid(DSZ/TX, DSZ/TY, NBATCH*NZC);   // 10 x 10 x 16 = 1600 blocks
    ncc_main<<<grid, BLK, 0, stream>>>(pred, tgt, ws);
    ncc_final<<<1, 1, 0, stream>>>(ws, out);
}

// Round 5
// 231.260 us; speedup vs baseline: 1.1869x; 1.1869x over previous
//
#include <hip/hip_runtime.h>

// NCC loss: 1 - mean( cross^2 / (pvar*tvar + 1e-8) ) over 9^3 zero-padded
// box windows, input (4,1,160,160,160) fp32.
//
// R5: R4's transposed s2 was 8-way bank-conflicted on y-reads -> reverted to
// R3's proven stride-20 [f][y][x] layout (<=2-way everywhere). Main change:
// the 9-slice subtract ring moves LDS -> REGISTERS (rp/rt[9][4], static
// indices via 4 prologue steps + 4 x unroll-9; slot sequence is 9-periodic).
// Removes all ring LDS traffic (~45% of the LDS pipe), LDS 50.7 -> 19.2 KB
// (s2 double-buffered -> ONE barrier per z-step), 4 blocks/CU instead of 3.

#define DSZ    160
#define NBATCH 4
#define RAD    4
#define TX     16
#define TY     16
#define ZCHUNK 40
#define SLICE  (DSZ*DSZ)
#define VOL    (DSZ*DSZ*DSZ)
#define WINV   (1.0f/729.0f)
#define NVOX_INV (1.0f/16384000.0f)

#define NROW 24        // halo rows per tile
#define NGRP 6         // x groups of 4 halo cols (24)
#define BLK  192

#define S2_RS 20                 // row stride: 16 outputs + pad (2-way banks)
#define S2_FS (NROW*S2_RS)       // 480 floats per field
#define S2_BUF (5*S2_FS)         // 2400 floats per parity buffer

__device__ __forceinline__ float dpp_shl1(float x) {  // lane i <- lane i+1 (16-lane row, OOB=0)
    return __int_as_float(__builtin_amdgcn_update_dpp(0, __float_as_int(x), 0x101, 0xf, 0xf, true));
}
__device__ __forceinline__ float dpp_shl2(float x) {  // lane i <- lane i+2
    return __int_as_float(__builtin_amdgcn_update_dpp(0, __float_as_int(x), 0x102, 0xf, 0xf, true));
}

__global__ __launch_bounds__(BLK, 3)
void ncc_main(const float* __restrict__ pred, const float* __restrict__ tgt,
              float* __restrict__ accum)
{
    const int tid = threadIdx.x;
    const int row = tid >> 3;      // 0..23 halo row
    const int g   = tid & 7;       // 0..7; g<6 = active x-group
    const int ox  = blockIdx.x * TX;
    const int oy  = blockIdx.y * TY;
    const int batch = blockIdx.z >> 2;
    const int z0  = (blockIdx.z & 3) * ZCHUNK;

    __shared__ float s2[2*S2_BUF];   // 19.2 KB, double-buffered [f][y][x pad20]

    const bool stg = (g < NGRP);
    const int  gy  = oy - RAD + row;
    const int  gx0 = ox - RAD + g*4;
    const bool ldok = stg && (gy >= 0) && (gy < DSZ) && (gx0 >= 0) && (gx0 + 3 < DSZ);
    const int  base = batch*VOL + gy*DSZ + gx0;     // only used under ldok

    // register ring of raw slice values (own 4 columns), chunk-local slots
    float rp[9][4], rt[9][4];
    float zs[5][4];
    #pragma unroll
    for (int k = 0; k < 9; ++k)
        #pragma unroll
        for (int j = 0; j < 4; ++j) { rp[k][j] = 0.f; rt[k][j] = 0.f; }
    #pragma unroll
    for (int f = 0; f < 5; ++f)
        #pragma unroll
        for (int j = 0; j < 4; ++j) zs[f][j] = 0.f;

    // ---- warm-up: chunk-local slices 0..7 (z = z0-4 .. z0+3) -> slots 0..7
    #pragma unroll
    for (int i = 0; i < 8; ++i) {
        int z = z0 - RAD + i;
        if (z >= 0) {                       // uniform; z < DSZ always here
            float4 p4 = {0,0,0,0}, t4 = {0,0,0,0};
            if (ldok) {
                p4 = *(const float4*)(pred + base + z*SLICE);
                t4 = *(const float4*)(tgt  + base + z*SLICE);
            }
            const float pc[4] = {p4.x,p4.y,p4.z,p4.w};
            const float tc[4] = {t4.x,t4.y,t4.z,t4.w};
            #pragma unroll
            for (int j = 0; j < 4; ++j) {
                zs[0][j] += pc[j];        zs[1][j] += tc[j];
                zs[2][j] += pc[j]*pc[j];  zs[3][j] += tc[j]*tc[j];
                zs[4][j] += pc[j]*tc[j];
                rp[i][j] = pc[j];  rt[i][j] = tc[j];
            }
        }
    }

    // ---- streaming prefetch of the next add-slice ----
    int za = z0 + RAD;                      // absolute z of next fetch
    int zmax = z0 + ZCHUNK + RAD;           // last useful slice + 1
    if (zmax > DSZ) zmax = DSZ;
    float4 pa4 = {0,0,0,0}, ta4 = {0,0,0,0};
    auto pf = [&]() {
        float4 p = {0,0,0,0}, t = {0,0,0,0};
        if (ldok && za < zmax) {
            p = *(const float4*)(pred + base + za*SLICE);
            t = *(const float4*)(tgt  + base + za*SLICE);
        }
        pa4 = p; ta4 = t; ++za;
    };
    pf();

    int pb = 1;          // parity buffer toggle (first step -> 0)
    float acc = 0.f;

#define NCC_STEP(SLOT) do {                                                   \
    pb ^= 1;                                                                  \
    float* s2w = s2 + pb*S2_BUF;                                              \
    if (stg) {                                                                \
        float pc[4] = {pa4.x,pa4.y,pa4.z,pa4.w};                              \
        float tc[4] = {ta4.x,ta4.y,ta4.z,ta4.w};                              \
        _Pragma("unroll")                                                     \
        for (int j = 0; j < 4; ++j) {                                         \
            float ps = rp[SLOT][j], qs = rt[SLOT][j];                         \
            float d0 = pc[j] - ps, d1 = tc[j] - qs;                           \
            zs[0][j] += d0;                                                   \
            zs[1][j] += d1;                                                   \
            zs[2][j] += d0*(pc[j] + ps);                                      \
            zs[3][j] += d1*(tc[j] + qs);                                      \
            zs[4][j] += pc[j]*tc[j] - ps*qs;                                  \
            rp[SLOT][j] = pc[j];  rt[SLOT][j] = tc[j];                        \
        }                                                                     \
        pf();   /* issue next slice's loads; drain behind the barrier */      \
        _Pragma("unroll")                                                     \
        for (int f = 0; f < 5; ++f) {                                         \
            float P0 = zs[f][0];                                              \
            float P1 = P0 + zs[f][1];                                         \
            float P2 = P1 + zs[f][2];                                         \
            float P3 = P2 + zs[f][3];                                         \
            float T  = dpp_shl1(P3);                                          \
            float Q0 = dpp_shl2(P0), Q1 = dpp_shl2(P1);                       \
            float Q2 = dpp_shl2(P2), Q3 = dpp_shl2(P3);                       \
            if (g < 4) {                                                      \
                float b = P3 + T;                                             \
                float* dst = &s2w[f*S2_FS + row*S2_RS + g*4];                 \
                dst[0] = b + Q0;                                              \
                dst[1] = b - P0 + Q1;                                         \
                dst[2] = b - P1 + Q2;                                         \
                dst[3] = b - P2 + Q3;                                         \
            }                                                                 \
        }                                                                     \
    }                                                                         \
    __syncthreads();                                                          \
    if (tid < 64) {                                                           \
        const int x = tid & 15, yq = (tid >> 4)*4;                            \
        float S[5][4];                                                        \
        _Pragma("unroll")                                                     \
        for (int f = 0; f < 5; ++f) {                                         \
            const float* col = &s2w[f*S2_FS + x];                             \
            float r0 = col[(yq+0)*S2_RS], r1 = col[(yq+1)*S2_RS];             \
            float r2 = col[(yq+2)*S2_RS], r3 = col[(yq+3)*S2_RS];             \
            float run = r0+r1+r2+r3 + col[(yq+4)*S2_RS] + col[(yq+5)*S2_RS]   \
                      + col[(yq+6)*S2_RS] + col[(yq+7)*S2_RS];                \
            run += col[(yq+8)*S2_RS];        S[f][0] = run;                   \
            run += col[(yq+9)*S2_RS]  - r0;  S[f][1] = run;                   \
            run += col[(yq+10)*S2_RS] - r1;  S[f][2] = run;                   \
            run += col[(yq+11)*S2_RS] - r2;  S[f][3] = run;                   \
        }                                                                     \
        _Pragma("unroll")                                                     \
        for (int i = 0; i < 4; ++i) {                                         \
            float Sp = S[0][i], St = S[1][i];                                 \
            float cross = S[4][i] - Sp*St*WINV;                               \
            float pv    = S[2][i] - Sp*Sp*WINV;                               \
            float tv    = S[3][i] - St*St*WINV;                               \
            acc += cross*cross / (pv*tv + 1e-8f);                             \
        }                                                                     \
    }                                                                         \
} while (0)

    // steps s=0..3: slots (s+8)%9 = 8,0,1,2
    NCC_STEP(8); NCC_STEP(0); NCC_STEP(1); NCC_STEP(2);
    // steps s=4..39: slot sequence (s+8)%9 is 9-periodic: 3,4,5,6,7,8,0,1,2
    for (int it = 0; it < 4; ++it) {
        NCC_STEP(3); NCC_STEP(4); NCC_STEP(5);
        NCC_STEP(6); NCC_STEP(7); NCC_STEP(8);
        NCC_STEP(0); NCC_STEP(1); NCC_STEP(2);
    }
#undef NCC_STEP

    // all cc partials live in wave 0
    if (tid < 64) {
        float v = acc;
        #pragma unroll
        for (int off = 32; off > 0; off >>= 1) v += __shfl_down(v, off, 64);
        if (tid == 0) atomicAdd(accum, v);
    }
}

__global__ void ncc_final(const float* __restrict__ accum, float* __restrict__ out)
{
    out[0] = 1.0f - accum[0] * NVOX_INV;
}

extern "C" void kernel_launch(void* const* d_in, const int* in_sizes, int n_in,
                              void* d_out, int out_size, void* d_ws, size_t ws_size,
                              hipStream_t stream)
{
    const float* pred = (const float*)d_in[0];
    const float* tgt  = (const float*)d_in[1];
    float* out = (float*)d_out;
    float* ws  = (float*)d_ws;

    hipMemsetAsync(ws, 0, sizeof(float), stream);
    dim3 grid(DSZ/TX, DSZ/TY, NBATCH*4);   // 10 x 10 x 16 = 1600 blocks
    ncc_main<<<grid, BLK, 0, stream>>>(pred, tgt, ws);
    ncc_final<<<1, 1, 0, stream>>>(ws, out);
}